// Round 1
// baseline (292.054 us; speedup 1.0000x reference)
//
#include <hip/hip_runtime.h>
#include <hip/hip_fp16.h>
#include <math.h>

#define N_NODES    50000
#define N_EDGES_IN 800000
#define N_EDGES    850000   // + self loops
#define N_GRAPHS   512
#define NEG_SLOPE  0.2f
#define EPS_F      1e-16f

#define NB_COARSE  196              // ceil(50000/256) coarse dst buckets
#define NSUB       8                // sub-regions per bucket (writer spread)
#define NBINS      (NB_COARSE*NSUB) // 1568
#define CAP        1024             // slots per (bucket,sub) region; max load ~810
#define GEMM_BLOCKS 391             // (N_NODES+127)/128

typedef _Float16 half8 __attribute__((ext_vector_type(8)));
typedef float    f32x4 __attribute__((ext_vector_type(4)));

// ---------------- MFMA GEMM: h[N,128] = x[N,128] @ W[128,128] + fused scores
// 128x128 tile, 256 thr = 4 waves (R7 structure, verified).
__global__ __launch_bounds__(256) void k_gemm(const void* __restrict__ xsrc,
                                              const int* __restrict__ ids,
                                              const float* __restrict__ W,
                                              const float* __restrict__ a_s,
                                              const float* __restrict__ a_d,
                                              _Float16* __restrict__ hH,
                                              float* __restrict__ as_,
                                              float* __restrict__ ad_) {
    __shared__ _Float16 WT[128][136];   // [n][k]
    __shared__ _Float16 Xs[128][72];    // [row][k within chunk]
    int t = threadIdx.x;
    int row0 = blockIdx.x * 128;
    int w = t >> 6, lane = t & 63;
    int n = lane & 15, quad = lane >> 4;

    #pragma unroll
    for (int i = 0; i < 16; i++) {
        int q = t + i * 256;
        int k = q >> 5;
        int n4 = (q & 31) * 4;
        float4 v = *(const float4*)(W + (size_t)k * 128 + n4);
        WT[n4 + 0][k] = (_Float16)v.x;
        WT[n4 + 1][k] = (_Float16)v.y;
        WT[n4 + 2][k] = (_Float16)v.z;
        WT[n4 + 3][k] = (_Float16)v.w;
    }

    f32x4 acc[2][8] = {};
    for (int kc = 0; kc < 2; kc++) {
        if (kc) __syncthreads();
        if (ids == nullptr) {
            const _Float16* xH = (const _Float16*)xsrc;
            #pragma unroll
            for (int i = 0; i < 4; i++) {
                int q = t + i * 256;
                int r = q >> 3, o8 = (q & 7) * 8;
                int gr = row0 + r; if (gr >= N_NODES) gr = N_NODES - 1;
                *(half8*)&Xs[r][o8] = *(const half8*)&xH[(size_t)gr * 128 + kc * 64 + o8];
            }
        } else {
            const float* xf = (const float*)xsrc;
            #pragma unroll
            for (int i = 0; i < 4; i++) {
                int q = t + i * 256;
                int r = q >> 3, o8 = (q & 7) * 8;
                int gr = row0 + r; if (gr >= N_NODES) gr = N_NODES - 1;
                const float* src = xf + (size_t)ids[gr] * 128 + kc * 64 + o8;
                float4 v0 = *(const float4*)src;
                float4 v1 = *(const float4*)(src + 4);
                half8 hv;
                hv[0] = (_Float16)v0.x; hv[1] = (_Float16)v0.y;
                hv[2] = (_Float16)v0.z; hv[3] = (_Float16)v0.w;
                hv[4] = (_Float16)v1.x; hv[5] = (_Float16)v1.y;
                hv[6] = (_Float16)v1.z; hv[7] = (_Float16)v1.w;
                *(half8*)&Xs[r][o8] = hv;
            }
        }
        __syncthreads();
        #pragma unroll
        for (int ks = 0; ks < 2; ks++) {
            int ko = ks * 32 + quad * 8;
            half8 a0 = *(const half8*)&Xs[w * 32 + n][ko];
            half8 a1 = *(const half8*)&Xs[w * 32 + 16 + n][ko];
            int kg = kc * 64 + ko;
            #pragma unroll
            for (int c = 0; c < 8; c++) {
                half8 b = *(const half8*)&WT[c * 16 + n][kg];
                acc[0][c] = __builtin_amdgcn_mfma_f32_16x16x32_f16(a0, b, acc[0][c], 0, 0, 0);
                acc[1][c] = __builtin_amdgcn_mfma_f32_16x16x32_f16(a1, b, acc[1][c], 0, 0, 0);
            }
        }
    }

    float sa[8], da[8];
    #pragma unroll
    for (int c = 0; c < 8; c++) { sa[c] = a_s[c * 16 + n]; da[c] = a_d[c * 16 + n]; }
    #pragma unroll
    for (int r = 0; r < 2; r++) {
        float ps[4] = {0.f, 0.f, 0.f, 0.f}, pd[4] = {0.f, 0.f, 0.f, 0.f};
        #pragma unroll
        for (int reg = 0; reg < 4; reg++) {
            int row = row0 + w * 32 + r * 16 + quad * 4 + reg;
            bool ok = row < N_NODES;
            #pragma unroll
            for (int c = 0; c < 8; c++) {
                float v = acc[r][c][reg];
                ps[reg] += v * sa[c];
                pd[reg] += v * da[c];
                if (ok) hH[(size_t)row * 128 + c * 16 + n] = (_Float16)v;
            }
        }
        #pragma unroll
        for (int off = 1; off < 16; off <<= 1) {
            #pragma unroll
            for (int reg = 0; reg < 4; reg++) {
                ps[reg] += __shfl_xor(ps[reg], off, 64);
                pd[reg] += __shfl_xor(pd[reg], off, 64);
            }
        }
        if (n == 0) {
            #pragma unroll
            for (int reg = 0; reg < 4; reg++) {
                int row = row0 + w * 32 + r * 16 + quad * 4 + reg;
                if (row < N_NODES) { as_[row] = ps[reg]; ad_[row] = pd[reg]; }
            }
        }
    }
}

// ---------------- CSR build, 2 kernels, fixed-capacity regions --------------
// pass 1: 4096 edges/block; per-(block,bucket) runs appended contiguously into
// region (bucket*NSUB+sub)*CAP via one global cursor bump per bucket per block.
__global__ __launch_bounds__(256) void k_scat1(const int* __restrict__ ei,
                                               int* __restrict__ gcur,
                                               int* __restrict__ recs) {
    __shared__ int lcnt[NB_COARSE];
    __shared__ int lbase[NB_COARSE];
    int t = threadIdx.x;
    int e0 = blockIdx.x * 4096;
    int sub = blockIdx.x & 7;
    for (int i = t; i < NB_COARSE; i += 256) lcnt[i] = 0;
    __syncthreads();
    int rec[16], b[16], r[16];
    #pragma unroll
    for (int i = 0; i < 16; i++) {
        int e = e0 + t + i * 256;
        if (e < N_EDGES) {
            int s, d;
            if (e < N_EDGES_IN) { s = ei[e]; d = ei[N_EDGES_IN + e]; }
            else                { s = e - N_EDGES_IN; d = s; }
            b[i] = d >> 8;
            rec[i] = s | ((d & 255) << 16);
            r[i] = atomicAdd(&lcnt[b[i]], 1);
        } else b[i] = -1;
    }
    __syncthreads();
    for (int i = t; i < NB_COARSE; i += 256) {
        int c = lcnt[i];
        lbase[i] = c ? atomicAdd(&gcur[i * NSUB + sub], c) : 0;
    }
    __syncthreads();
    #pragma unroll
    for (int i = 0; i < 16; i++)
        if (b[i] >= 0) recs[(b[i] * NSUB + sub) * CAP + lbase[b[i]] + r[i]] = rec[i];
}

// pass 2: one block per coarse bucket. Computes its global base from the final
// cursors (no separate scan kernel), fine-sorts by dst, writes row_ptr + srcs.
__global__ __launch_bounds__(256) void k_scat2(const int* __restrict__ recs,
                                               const int* __restrict__ gcur,
                                               int* __restrict__ row_ptr,
                                               int* __restrict__ srcs) {
    __shared__ int scnt[NBINS];     // final per-(bucket,sub) counts
    __shared__ int bcnt[256];       // per-bucket totals -> inclusive scan
    __shared__ int hist[256];
    __shared__ int off2[256];
    __shared__ int rank[256];
    int b = blockIdx.x, t = threadIdx.x;
    for (int i = t; i < NBINS; i += 256) scnt[i] = gcur[i];
    hist[t] = 0; rank[t] = 0;
    __syncthreads();
    int tot = 0;
    if (t < NB_COARSE) {
        #pragma unroll
        for (int s = 0; s < NSUB; s++) tot += scnt[t * NSUB + s];
    }
    bcnt[t] = tot;
    __syncthreads();
    for (int o = 1; o < 256; o <<= 1) {
        int x = (t >= o) ? bcnt[t - o] : 0;
        __syncthreads(); bcnt[t] += x; __syncthreads();
    }
    int lo = (b == 0) ? 0 : bcnt[b - 1];
    // fine histogram over this bucket's records
    for (int s = 0; s < NSUB; s++) {
        int c = scnt[b * NSUB + s];
        const int* reg = &recs[(b * NSUB + s) * CAP];
        for (int i = t; i < c; i += 256) atomicAdd(&hist[reg[i] >> 16], 1);
    }
    __syncthreads();
    int v = hist[t];
    off2[t] = v; __syncthreads();
    for (int o = 1; o < 256; o <<= 1) {
        int x = (t >= o) ? off2[t - o] : 0;
        __syncthreads(); off2[t] += x; __syncthreads();
    }
    int excl = off2[t] - v;
    int dglob = b * 256 + t;
    if (dglob < N_NODES) row_ptr[dglob] = lo + excl;
    if (b == 0 && t == 0) row_ptr[N_NODES] = N_EDGES;
    __syncthreads();
    off2[t] = excl;
    __syncthreads();
    for (int s = 0; s < NSUB; s++) {
        int c = scnt[b * NSUB + s];
        const int* reg = &recs[(b * NSUB + s) * CAP];
        for (int i = t; i < c; i += 256) {
            int rec = reg[i];
            int dl = rec >> 16;
            int rk = atomicAdd(&rank[dl], 1);
            srcs[lo + off2[dl] + rk] = rec & 0xFFFF;
        }
    }
}

// ---------------- softmax + weighted aggregation, 16 lanes per dst ----------
__global__ __launch_bounds__(256) void k_aggregate(
        const float4* __restrict__ h16,
        const float* __restrict__ as_,
        const float* __restrict__ ad_, const int* __restrict__ row_ptr,
        const int* __restrict__ srcs, const float4* __restrict__ bias4,
        float4* __restrict__ xout16, int do_relu) {
    int d = (blockIdx.x * blockDim.x + threadIdx.x) >> 4;
    if (d >= N_NODES) return;
    int lane = threadIdx.x & 63;
    int gl   = lane & 15;
    int base = lane & 48;
    int lo = row_ptr[d], hi = row_ptr[d + 1];
    int deg = hi - lo;             // >= 1 (self-loop)
    float add = ad_[d];

    float eC[4]; int sC[4];
    float m_l = -1e30f, s_l = 0.f;
    #pragma unroll
    for (int c = 0; c < 4; c++) {
        float e = -1e30f; int sidx = 0;
        int j = c * 16 + gl;
        if (j < deg) {
            sidx = __builtin_nontemporal_load(&srcs[lo + j]);
            e = as_[sidx] + add;
            e = (e > 0.f) ? e : NEG_SLOPE * e;
            float nm = fmaxf(m_l, e);
            s_l = s_l * __expf(m_l - nm) + __expf(e - nm);
            m_l = nm;
        }
        eC[c] = e; sC[c] = sidx;
    }
    for (int j0 = 64; j0 < deg; j0 += 16) {
        int j = j0 + gl;
        if (j < deg) {
            int sidx = __builtin_nontemporal_load(&srcs[lo + j]);
            float e = as_[sidx] + add;
            e = (e > 0.f) ? e : NEG_SLOPE * e;
            float nm = fmaxf(m_l, e);
            s_l = s_l * __expf(m_l - nm) + __expf(e - nm);
            m_l = nm;
        }
    }
    float m = m_l, s = s_l;
    #pragma unroll
    for (int off = 8; off; off >>= 1) {
        float om = __shfl_xor(m, off, 64);
        float os = __shfl_xor(s, off, 64);
        float nm = fmaxf(m, om);
        s = s * __expf(m - nm) + os * __expf(om - nm);
        m = nm;
    }
    float inv = 1.f / (s + EPS_F);

    float4 acc0 = make_float4(0.f, 0.f, 0.f, 0.f);
    float4 acc1 = make_float4(0.f, 0.f, 0.f, 0.f);
    #pragma unroll
    for (int c = 0; c < 4; c++) {
        int j0 = c * 16;
        if (j0 >= deg) break;
        float w = __expf(eC[c] - m) * inv;
        int sidx = sC[c];
        int cnt = min(16, deg - j0);
        for (int jj = 0; jj < cnt; jj += 4) {
            float w0 = __shfl(w, base + jj + 0, 64); int s0 = __shfl(sidx, base + jj + 0, 64);
            float w1 = __shfl(w, base + jj + 1, 64); int s1 = __shfl(sidx, base + jj + 1, 64);
            float w2 = __shfl(w, base + jj + 2, 64); int s2 = __shfl(sidx, base + jj + 2, 64);
            float w3 = __shfl(w, base + jj + 3, 64); int s3 = __shfl(sidx, base + jj + 3, 64);
            float4 r0 = h16[(size_t)s0 * 16 + gl];
            float4 r1 = h16[(size_t)s1 * 16 + gl];
            float4 r2 = h16[(size_t)s2 * 16 + gl];
            float4 r3 = h16[(size_t)s3 * 16 + gl];
            const __half2* p;
            float2 f0, f1, f2, f3;
            p = (const __half2*)&r0;
            f0 = __half22float2(p[0]); f1 = __half22float2(p[1]);
            f2 = __half22float2(p[2]); f3 = __half22float2(p[3]);
            acc0.x += w0*f0.x; acc0.y += w0*f0.y; acc0.z += w0*f1.x; acc0.w += w0*f1.y;
            acc1.x += w0*f2.x; acc1.y += w0*f2.y; acc1.z += w0*f3.x; acc1.w += w0*f3.y;
            p = (const __half2*)&r1;
            f0 = __half22float2(p[0]); f1 = __half22float2(p[1]);
            f2 = __half22float2(p[2]); f3 = __half22float2(p[3]);
            acc0.x += w1*f0.x; acc0.y += w1*f0.y; acc0.z += w1*f1.x; acc0.w += w1*f1.y;
            acc1.x += w1*f2.x; acc1.y += w1*f2.y; acc1.z += w1*f3.x; acc1.w += w1*f3.y;
            p = (const __half2*)&r2;
            f0 = __half22float2(p[0]); f1 = __half22float2(p[1]);
            f2 = __half22float2(p[2]); f3 = __half22float2(p[3]);
            acc0.x += w2*f0.x; acc0.y += w2*f0.y; acc0.z += w2*f1.x; acc0.w += w2*f1.y;
            acc1.x += w2*f2.x; acc1.y += w2*f2.y; acc1.z += w2*f3.x; acc1.w += w2*f3.y;
            p = (const __half2*)&r3;
            f0 = __half22float2(p[0]); f1 = __half22float2(p[1]);
            f2 = __half22float2(p[2]); f3 = __half22float2(p[3]);
            acc0.x += w3*f0.x; acc0.y += w3*f0.y; acc0.z += w3*f1.x; acc0.w += w3*f1.y;
            acc1.x += w3*f2.x; acc1.y += w3*f2.y; acc1.z += w3*f3.x; acc1.w += w3*f3.y;
        }
    }
    for (int j0 = 64; j0 < deg; j0 += 16) {
        int j = j0 + gl;
        float w = 0.f; int sidx = 0;
        if (j < deg) {
            int si = __builtin_nontemporal_load(&srcs[lo + j]);
            float e = as_[si] + add;
            e = (e > 0.f) ? e : NEG_SLOPE * e;
            w = __expf(e - m) * inv;
            sidx = si;
        }
        int cnt = min(16, deg - j0);
        for (int jj = 0; jj < cnt; jj++) {
            float w0 = __shfl(w, base + jj, 64); int s0 = __shfl(sidx, base + jj, 64);
            float4 r0 = h16[(size_t)s0 * 16 + gl];
            const __half2* p = (const __half2*)&r0;
            float2 f0 = __half22float2(p[0]), f1 = __half22float2(p[1]);
            float2 f2 = __half22float2(p[2]), f3 = __half22float2(p[3]);
            acc0.x += w0*f0.x; acc0.y += w0*f0.y; acc0.z += w0*f1.x; acc0.w += w0*f1.y;
            acc1.x += w0*f2.x; acc1.y += w0*f2.y; acc1.z += w0*f3.x; acc1.w += w0*f3.y;
        }
    }
    float4 b0 = bias4[gl * 2], b1 = bias4[gl * 2 + 1];
    float4 o0 = make_float4(acc0.x + b0.x, acc0.y + b0.y, acc0.z + b0.z, acc0.w + b0.w);
    float4 o1 = make_float4(acc1.x + b1.x, acc1.y + b1.y, acc1.z + b1.z, acc1.w + b1.w);
    if (do_relu) {
        o0.x = fmaxf(o0.x, 0.f); o0.y = fmaxf(o0.y, 0.f);
        o0.z = fmaxf(o0.z, 0.f); o0.w = fmaxf(o0.w, 0.f);
        o1.x = fmaxf(o1.x, 0.f); o1.y = fmaxf(o1.y, 0.f);
        o1.z = fmaxf(o1.z, 0.f); o1.w = fmaxf(o1.w, 0.f);
    }
    union { __half2 h2[4]; float4 f; } pk;
    pk.h2[0] = __floats2half2_rn(o0.x, o0.y);
    pk.h2[1] = __floats2half2_rn(o0.z, o0.w);
    pk.h2[2] = __floats2half2_rn(o1.x, o1.y);
    pk.h2[3] = __floats2half2_rn(o1.z, o1.w);
    xout16[(size_t)d * 16 + gl] = pk.f;
}

// ---------------- global mean pool over fp16 x (batch is sorted) ------------
__global__ __launch_bounds__(512) void k_pool(const __half* __restrict__ x,
                                              const int* __restrict__ batch,
                                              float* __restrict__ out) {
    __shared__ float red[512];
    __shared__ int sh[2];
    int g = blockIdx.x;
    int t = threadIdx.x;
    if (t == 0) {
        int lo = 0, hi = N_NODES;
        while (lo < hi) { int mid = (lo + hi) >> 1; if (batch[mid] < g) lo = mid + 1; else hi = mid; }
        sh[0] = lo;
        int lo2 = lo, hi2 = N_NODES;
        while (lo2 < hi2) { int mid = (lo2 + hi2) >> 1; if (batch[mid] < g + 1) lo2 = mid + 1; else hi2 = mid; }
        sh[1] = lo2;
    }
    __syncthreads();
    int lo = sh[0], hi = sh[1];
    int sub = t >> 7, dim = t & 127;
    float sum = 0.f;
    for (int i = lo + sub; i < hi; i += 4) sum += __half2float(x[(size_t)i * 128 + dim]);
    red[t] = sum;
    __syncthreads();
    if (t < 128) {
        float s = red[t] + red[t + 128] + red[t + 256] + red[t + 384];
        int cnt = hi - lo;
        out[g * 128 + t] = s * (cnt > 0 ? 1.f / (float)cnt : 1.f);
    }
}

extern "C" void kernel_launch(void* const* d_in, const int* in_sizes, int n_in,
                              void* d_out, int out_size, void* d_ws, size_t ws_size,
                              hipStream_t stream) {
    const int*   node_ids   = (const int*)d_in[0];
    const int*   edge_index = (const int*)d_in[1];   // [2][800000]
    const int*   batch      = (const int*)d_in[2];
    const float* emb        = (const float*)d_in[3];
    const float* W[3]  = {(const float*)d_in[4],  (const float*)d_in[8],  (const float*)d_in[12]};
    const float* As[3] = {(const float*)d_in[5],  (const float*)d_in[9],  (const float*)d_in[13]};
    const float* Ad[3] = {(const float*)d_in[6],  (const float*)d_in[10], (const float*)d_in[14]};
    const float* Bs[3] = {(const float*)d_in[7],  (const float*)d_in[11], (const float*)d_in[15]};

    char* ws = (char*)d_ws;
    size_t off = 0;
    auto alloc = [&](size_t bytes) {
        void* p = ws + off; off += (bytes + 255) & ~(size_t)255; return p;
    };
    _Float16* xH    = (_Float16*)alloc((size_t)N_NODES * 128 * 2);  // activations (fp16)
    _Float16* hH    = (_Float16*)alloc((size_t)N_NODES * 128 * 2);  // h gather table (fp16)
    float*  as_     = (float*)alloc((size_t)N_NODES * 4);
    float*  ad_     = (float*)alloc((size_t)N_NODES * 4);
    int*    gcur    = (int*)alloc((size_t)NBINS * 4);        // zeroed cursors
    int*    row_ptr = (int*)alloc((size_t)(N_NODES + 1) * 4);
    int*    recs    = (int*)alloc((size_t)NBINS * CAP * 4);  // 6.4 MB fixed regions
    int*    srcs    = (int*)alloc((size_t)N_EDGES * 4);
    (void)ws_size; (void)in_sizes; (void)n_in; (void)out_size;

    hipMemsetAsync(gcur, 0, (size_t)NBINS * 4, stream);

    // CSR build: 2 kernels, fixed-capacity regions (no histogram/scan kernels)
    k_scat1<<<(N_EDGES + 4095) / 4096, 256, 0, stream>>>(edge_index, gcur, recs);
    k_scat2<<<NB_COARSE, 256, 0, stream>>>(recs, gcur, row_ptr, srcs);

    for (int l = 0; l < 3; l++) {
        k_gemm<<<GEMM_BLOCKS, 256, 0, stream>>>(
                 (l == 0) ? (const void*)emb : (const void*)xH,
                 (l == 0) ? node_ids : nullptr,
                 W[l], As[l], Ad[l], hH, as_, ad_);
        k_aggregate<<<(N_NODES * 16 + 255) / 256, 256, 0, stream>>>((const float4*)hH,
                 as_, ad_, row_ptr, srcs, (const float4*)Bs[l], (float4*)xH,
                 (l < 2) ? 1 : 0);
    }
    k_pool<<<N_GRAPHS, 512, 0, stream>>>((const __half*)xH, batch, (float*)d_out);
}

// Round 7
// 283.395 us; speedup vs baseline: 1.0306x; 1.0306x over previous
//
#include <hip/hip_runtime.h>
#include <hip/hip_fp16.h>
#include <math.h>

#define N_NODES    50000
#define N_EDGES_IN 800000
#define N_EDGES    850000   // + self loops
#define N_GRAPHS   512
#define NEG_SLOPE  0.2f
#define EPS_F      1e-16f

#define NB_COARSE  196              // ceil(50000/256) coarse dst buckets
#define NSUB       8                // sub-regions per bucket (writer spread)
#define NBINS      (NB_COARSE*NSUB) // 1568
#define CAP        1024             // slots per (bucket,sub) region; max load ~810
#define GEMM_BLOCKS 391             // (N_NODES+127)/128

typedef _Float16 half8 __attribute__((ext_vector_type(8)));
typedef float    f32x4 __attribute__((ext_vector_type(4)));

// ---------------- MFMA GEMM body: h[N,128] = x[N,128] @ W[128,128] + scores
// 128x128 tile, 256 thr = 4 waves. GATHER=true: fp32 emb rows via ids.
// GATHER=false: fp16 xH rows, ids unused.
template<bool GATHER>
__device__ __forceinline__ void gemm_body(
        _Float16 (* __restrict__ WT)[136],   // [n][k]
        _Float16 (* __restrict__ Xs)[72],    // [row][k within chunk]
        const void* __restrict__ xsrc,
        const int* __restrict__ ids,
        const float* __restrict__ W,
        const float* __restrict__ a_s,
        const float* __restrict__ a_d,
        _Float16* __restrict__ hH,
        float* __restrict__ as_,
        float* __restrict__ ad_,
        int blk) {
    int t = threadIdx.x;
    int row0 = blk * 128;
    int w = t >> 6, lane = t & 63;
    int n = lane & 15, quad = lane >> 4;

    #pragma unroll
    for (int i = 0; i < 16; i++) {
        int q = t + i * 256;
        int k = q >> 5;
        int n4 = (q & 31) * 4;
        float4 v = *(const float4*)(W + (size_t)k * 128 + n4);
        WT[n4 + 0][k] = (_Float16)v.x;
        WT[n4 + 1][k] = (_Float16)v.y;
        WT[n4 + 2][k] = (_Float16)v.z;
        WT[n4 + 3][k] = (_Float16)v.w;
    }

    f32x4 acc[2][8] = {};
    for (int kc = 0; kc < 2; kc++) {
        if (kc) __syncthreads();
        if (!GATHER) {
            const _Float16* xH = (const _Float16*)xsrc;
            #pragma unroll
            for (int i = 0; i < 4; i++) {
                int q = t + i * 256;
                int r = q >> 3, o8 = (q & 7) * 8;
                int gr = row0 + r; if (gr >= N_NODES) gr = N_NODES - 1;
                *(half8*)&Xs[r][o8] = *(const half8*)&xH[(size_t)gr * 128 + kc * 64 + o8];
            }
        } else {
            const float* xf = (const float*)xsrc;
            #pragma unroll
            for (int i = 0; i < 4; i++) {
                int q = t + i * 256;
                int r = q >> 3, o8 = (q & 7) * 8;
                int gr = row0 + r; if (gr >= N_NODES) gr = N_NODES - 1;
                const float* src = xf + (size_t)ids[gr] * 128 + kc * 64 + o8;
                float4 v0 = *(const float4*)src;
                float4 v1 = *(const float4*)(src + 4);
                half8 hv;
                hv[0] = (_Float16)v0.x; hv[1] = (_Float16)v0.y;
                hv[2] = (_Float16)v0.z; hv[3] = (_Float16)v0.w;
                hv[4] = (_Float16)v1.x; hv[5] = (_Float16)v1.y;
                hv[6] = (_Float16)v1.z; hv[7] = (_Float16)v1.w;
                *(half8*)&Xs[r][o8] = hv;
            }
        }
        __syncthreads();
        #pragma unroll
        for (int ks = 0; ks < 2; ks++) {
            int ko = ks * 32 + quad * 8;
            half8 a0 = *(const half8*)&Xs[w * 32 + n][ko];
            half8 a1 = *(const half8*)&Xs[w * 32 + 16 + n][ko];
            int kg = kc * 64 + ko;
            #pragma unroll
            for (int c = 0; c < 8; c++) {
                half8 b = *(const half8*)&WT[c * 16 + n][kg];
                acc[0][c] = __builtin_amdgcn_mfma_f32_16x16x32_f16(a0, b, acc[0][c], 0, 0, 0);
                acc[1][c] = __builtin_amdgcn_mfma_f32_16x16x32_f16(a1, b, acc[1][c], 0, 0, 0);
            }
        }
    }

    float sa[8], da[8];
    #pragma unroll
    for (int c = 0; c < 8; c++) { sa[c] = a_s[c * 16 + n]; da[c] = a_d[c * 16 + n]; }
    #pragma unroll
    for (int r = 0; r < 2; r++) {
        float ps[4] = {0.f, 0.f, 0.f, 0.f}, pd[4] = {0.f, 0.f, 0.f, 0.f};
        #pragma unroll
        for (int reg = 0; reg < 4; reg++) {
            int row = row0 + w * 32 + r * 16 + quad * 4 + reg;
            bool ok = row < N_NODES;
            #pragma unroll
            for (int c = 0; c < 8; c++) {
                float v = acc[r][c][reg];
                ps[reg] += v * sa[c];
                pd[reg] += v * da[c];
                if (ok) hH[(size_t)row * 128 + c * 16 + n] = (_Float16)v;
            }
        }
        #pragma unroll
        for (int off = 1; off < 16; off <<= 1) {
            #pragma unroll
            for (int reg = 0; reg < 4; reg++) {
                ps[reg] += __shfl_xor(ps[reg], off, 64);
                pd[reg] += __shfl_xor(pd[reg], off, 64);
            }
        }
        if (n == 0) {
            #pragma unroll
            for (int reg = 0; reg < 4; reg++) {
                int row = row0 + w * 32 + r * 16 + quad * 4 + reg;
                if (row < N_NODES) { as_[row] = ps[reg]; ad_[row] = pd[reg]; }
            }
        }
    }
}

// scat2 body: one block per coarse bucket. Computes its global base from the
// final cursors, fine-sorts by dst, writes row_ptr + srcs.
__device__ __forceinline__ void scat2_body(
        int* __restrict__ scnt,   // [NBINS]
        int* __restrict__ bcnt,   // [256]
        int* __restrict__ hist,   // [256]
        int* __restrict__ off2,   // [256]
        int* __restrict__ rank,   // [256]
        const int* __restrict__ recs,
        const int* __restrict__ gcur,
        int* __restrict__ row_ptr,
        int* __restrict__ srcs,
        int b) {
    int t = threadIdx.x;
    for (int i = t; i < NBINS; i += 256) scnt[i] = gcur[i];
    hist[t] = 0; rank[t] = 0;
    __syncthreads();
    int tot = 0;
    if (t < NB_COARSE) {
        #pragma unroll
        for (int s = 0; s < NSUB; s++) tot += scnt[t * NSUB + s];
    }
    bcnt[t] = tot;
    __syncthreads();
    for (int o = 1; o < 256; o <<= 1) {
        int x = (t >= o) ? bcnt[t - o] : 0;
        __syncthreads(); bcnt[t] += x; __syncthreads();
    }
    int lo = (b == 0) ? 0 : bcnt[b - 1];
    // fine histogram over this bucket's records
    for (int s = 0; s < NSUB; s++) {
        int c = scnt[b * NSUB + s];
        const int* reg = &recs[(b * NSUB + s) * CAP];
        for (int i = t; i < c; i += 256) atomicAdd(&hist[reg[i] >> 16], 1);
    }
    __syncthreads();
    int v = hist[t];
    off2[t] = v; __syncthreads();
    for (int o = 1; o < 256; o <<= 1) {
        int x = (t >= o) ? off2[t - o] : 0;
        __syncthreads(); off2[t] += x; __syncthreads();
    }
    int excl = off2[t] - v;
    int dglob = b * 256 + t;
    if (dglob < N_NODES) row_ptr[dglob] = lo + excl;
    if (b == 0 && t == 0) row_ptr[N_NODES] = N_EDGES;
    __syncthreads();
    off2[t] = excl;
    __syncthreads();
    for (int s = 0; s < NSUB; s++) {
        int c = scnt[b * NSUB + s];
        const int* reg = &recs[(b * NSUB + s) * CAP];
        for (int i = t; i < c; i += 256) {
            int rec = reg[i];
            int dl = rec >> 16;
            int rk = atomicAdd(&rank[dl], 1);
            srcs[lo + off2[dl] + rk] = rec & 0xFFFF;
        }
    }
}

// ---------------- standalone GEMM (layers 1,2: fp16 x, no gather) -----------
__global__ __launch_bounds__(256) void k_gemm(const void* __restrict__ xsrc,
                                              const float* __restrict__ W,
                                              const float* __restrict__ a_s,
                                              const float* __restrict__ a_d,
                                              _Float16* __restrict__ hH,
                                              float* __restrict__ as_,
                                              float* __restrict__ ad_) {
    __shared__ _Float16 WT[128][136];
    __shared__ _Float16 Xs[128][72];
    gemm_body<false>(WT, Xs, xsrc, nullptr, W, a_s, a_d, hH, as_, ad_, blockIdx.x);
}

// ---------------- fused: gemm layer-0 (blocks 0..390) || scat2 (391..586) ---
// gemm0 (emb gather) is independent of the CSR build; scat2 only needs scat1's
// output. Running them in one dispatch hides scat2's 0.77-blocks/CU latency
// behind gemm0.
__global__ __launch_bounds__(256) void k_gemm0_scat2(
        const float* __restrict__ emb,
        const int* __restrict__ ids,
        const float* __restrict__ W,
        const float* __restrict__ a_s,
        const float* __restrict__ a_d,
        _Float16* __restrict__ hH,
        float* __restrict__ as_,
        float* __restrict__ ad_,
        const int* __restrict__ recs,
        const int* __restrict__ gcur,
        int* __restrict__ row_ptr,
        int* __restrict__ srcs) {
    __shared__ __align__(16) char smem[53248];   // gemm: 34816 + 18432
    if (blockIdx.x < GEMM_BLOCKS) {
        _Float16 (*WT)[136] = (_Float16(*)[136])smem;
        _Float16 (*Xs)[72]  = (_Float16(*)[72])(smem + 34816);
        gemm_body<true>(WT, Xs, emb, ids, W, a_s, a_d, hH, as_, ad_, blockIdx.x);
    } else {
        int* scnt = (int*)smem;           // NBINS
        int* bcnt = scnt + NBINS;         // 256
        int* hist = bcnt + 256;           // 256
        int* off2 = hist + 256;           // 256
        int* rank = off2 + 256;           // 256  (total 10368 B)
        scat2_body(scnt, bcnt, hist, off2, rank, recs, gcur, row_ptr, srcs,
                   blockIdx.x - GEMM_BLOCKS);
    }
}

// ---------------- CSR build pass 1 ------------------------------------------
// 4096 edges/block; per-(block,bucket) runs appended contiguously into region
// (bucket*NSUB+sub)*CAP via one global cursor bump per bucket per block.
__global__ __launch_bounds__(256) void k_scat1(const int* __restrict__ ei,
                                               int* __restrict__ gcur,
                                               int* __restrict__ recs) {
    __shared__ int lcnt[NB_COARSE];
    __shared__ int lbase[NB_COARSE];
    int t = threadIdx.x;
    int e0 = blockIdx.x * 4096;
    int sub = blockIdx.x & 7;
    for (int i = t; i < NB_COARSE; i += 256) lcnt[i] = 0;
    __syncthreads();
    int rec[16], b[16], r[16];
    #pragma unroll
    for (int i = 0; i < 16; i++) {
        int e = e0 + t + i * 256;
        if (e < N_EDGES) {
            int s, d;
            if (e < N_EDGES_IN) { s = ei[e]; d = ei[N_EDGES_IN + e]; }
            else                { s = e - N_EDGES_IN; d = s; }
            b[i] = d >> 8;
            rec[i] = s | ((d & 255) << 16);
            r[i] = atomicAdd(&lcnt[b[i]], 1);
        } else b[i] = -1;
    }
    __syncthreads();
    for (int i = t; i < NB_COARSE; i += 256) {
        int c = lcnt[i];
        lbase[i] = c ? atomicAdd(&gcur[i * NSUB + sub], c) : 0;
    }
    __syncthreads();
    #pragma unroll
    for (int i = 0; i < 16; i++)
        if (b[i] >= 0) recs[(b[i] * NSUB + sub) * CAP + lbase[b[i]] + r[i]] = rec[i];
}

// ---------------- softmax + weighted aggregation, 16 lanes per dst ----------
__global__ __launch_bounds__(256) void k_aggregate(
        const float4* __restrict__ h16,
        const float* __restrict__ as_,
        const float* __restrict__ ad_, const int* __restrict__ row_ptr,
        const int* __restrict__ srcs, const float4* __restrict__ bias4,
        float4* __restrict__ xout16, int do_relu) {
    int d = (blockIdx.x * blockDim.x + threadIdx.x) >> 4;
    if (d >= N_NODES) return;
    int lane = threadIdx.x & 63;
    int gl   = lane & 15;
    int base = lane & 48;
    int lo = row_ptr[d], hi = row_ptr[d + 1];
    int deg = hi - lo;             // >= 1 (self-loop)
    float add = ad_[d];

    float eC[4]; int sC[4];
    float m_l = -1e30f, s_l = 0.f;
    #pragma unroll
    for (int c = 0; c < 4; c++) {
        float e = -1e30f; int sidx = 0;
        int j = c * 16 + gl;
        if (j < deg) {
            sidx = __builtin_nontemporal_load(&srcs[lo + j]);
            e = as_[sidx] + add;
            e = (e > 0.f) ? e : NEG_SLOPE * e;
            float nm = fmaxf(m_l, e);
            s_l = s_l * __expf(m_l - nm) + __expf(e - nm);
            m_l = nm;
        }
        eC[c] = e; sC[c] = sidx;
    }
    for (int j0 = 64; j0 < deg; j0 += 16) {
        int j = j0 + gl;
        if (j < deg) {
            int sidx = __builtin_nontemporal_load(&srcs[lo + j]);
            float e = as_[sidx] + add;
            e = (e > 0.f) ? e : NEG_SLOPE * e;
            float nm = fmaxf(m_l, e);
            s_l = s_l * __expf(m_l - nm) + __expf(e - nm);
            m_l = nm;
        }
    }
    float m = m_l, s = s_l;
    #pragma unroll
    for (int off = 8; off; off >>= 1) {
        float om = __shfl_xor(m, off, 64);
        float os = __shfl_xor(s, off, 64);
        float nm = fmaxf(m, om);
        s = s * __expf(m - nm) + os * __expf(om - nm);
        m = nm;
    }
    float inv = 1.f / (s + EPS_F);

    float4 acc0 = make_float4(0.f, 0.f, 0.f, 0.f);
    float4 acc1 = make_float4(0.f, 0.f, 0.f, 0.f);
    #pragma unroll
    for (int c = 0; c < 4; c++) {
        int j0 = c * 16;
        if (j0 >= deg) break;
        float w = __expf(eC[c] - m) * inv;
        int sidx = sC[c];
        int cnt = min(16, deg - j0);
        for (int jj = 0; jj < cnt; jj += 4) {
            float w0 = __shfl(w, base + jj + 0, 64); int s0 = __shfl(sidx, base + jj + 0, 64);
            float w1 = __shfl(w, base + jj + 1, 64); int s1 = __shfl(sidx, base + jj + 1, 64);
            float w2 = __shfl(w, base + jj + 2, 64); int s2 = __shfl(sidx, base + jj + 2, 64);
            float w3 = __shfl(w, base + jj + 3, 64); int s3 = __shfl(sidx, base + jj + 3, 64);
            float4 r0 = h16[(size_t)s0 * 16 + gl];
            float4 r1 = h16[(size_t)s1 * 16 + gl];
            float4 r2 = h16[(size_t)s2 * 16 + gl];
            float4 r3 = h16[(size_t)s3 * 16 + gl];
            const __half2* p;
            float2 f0, f1, f2, f3;
            p = (const __half2*)&r0;
            f0 = __half22float2(p[0]); f1 = __half22float2(p[1]);
            f2 = __half22float2(p[2]); f3 = __half22float2(p[3]);
            acc0.x += w0*f0.x; acc0.y += w0*f0.y; acc0.z += w0*f1.x; acc0.w += w0*f1.y;
            acc1.x += w0*f2.x; acc1.y += w0*f2.y; acc1.z += w0*f3.x; acc1.w += w0*f3.y;
            p = (const __half2*)&r1;
            f0 = __half22float2(p[0]); f1 = __half22float2(p[1]);
            f2 = __half22float2(p[2]); f3 = __half22float2(p[3]);
            acc0.x += w1*f0.x; acc0.y += w1*f0.y; acc0.z += w1*f1.x; acc0.w += w1*f1.y;
            acc1.x += w1*f2.x; acc1.y += w1*f2.y; acc1.z += w1*f3.x; acc1.w += w1*f3.y;
            p = (const __half2*)&r2;
            f0 = __half22float2(p[0]); f1 = __half22float2(p[1]);
            f2 = __half22float2(p[2]); f3 = __half22float2(p[3]);
            acc0.x += w2*f0.x; acc0.y += w2*f0.y; acc0.z += w2*f1.x; acc0.w += w2*f1.y;
            acc1.x += w2*f2.x; acc1.y += w2*f2.y; acc1.z += w2*f3.x; acc1.w += w2*f3.y;
            p = (const __half2*)&r3;
            f0 = __half22float2(p[0]); f1 = __half22float2(p[1]);
            f2 = __half22float2(p[2]); f3 = __half22float2(p[3]);
            acc0.x += w3*f0.x; acc0.y += w3*f0.y; acc0.z += w3*f1.x; acc0.w += w3*f1.y;
            acc1.x += w3*f2.x; acc1.y += w3*f2.y; acc1.z += w3*f3.x; acc1.w += w3*f3.y;
        }
    }
    for (int j0 = 64; j0 < deg; j0 += 16) {
        int j = j0 + gl;
        float w = 0.f; int sidx = 0;
        if (j < deg) {
            int si = __builtin_nontemporal_load(&srcs[lo + j]);
            float e = as_[si] + add;
            e = (e > 0.f) ? e : NEG_SLOPE * e;
            w = __expf(e - m) * inv;
            sidx = si;
        }
        int cnt = min(16, deg - j0);
        for (int jj = 0; jj < cnt; jj++) {
            float w0 = __shfl(w, base + jj, 64); int s0 = __shfl(sidx, base + jj, 64);
            float4 r0 = h16[(size_t)s0 * 16 + gl];
            const __half2* p = (const __half2*)&r0;
            float2 f0 = __half22float2(p[0]), f1 = __half22float2(p[1]);
            float2 f2 = __half22float2(p[2]), f3 = __half22float2(p[3]);
            acc0.x += w0*f0.x; acc0.y += w0*f0.y; acc0.z += w0*f1.x; acc0.w += w0*f1.y;
            acc1.x += w0*f2.x; acc1.y += w0*f2.y; acc1.z += w0*f3.x; acc1.w += w0*f3.y;
        }
    }
    float4 b0 = bias4[gl * 2], b1 = bias4[gl * 2 + 1];
    float4 o0 = make_float4(acc0.x + b0.x, acc0.y + b0.y, acc0.z + b0.z, acc0.w + b0.w);
    float4 o1 = make_float4(acc1.x + b1.x, acc1.y + b1.y, acc1.z + b1.z, acc1.w + b1.w);
    if (do_relu) {
        o0.x = fmaxf(o0.x, 0.f); o0.y = fmaxf(o0.y, 0.f);
        o0.z = fmaxf(o0.z, 0.f); o0.w = fmaxf(o0.w, 0.f);
        o1.x = fmaxf(o1.x, 0.f); o1.y = fmaxf(o1.y, 0.f);
        o1.z = fmaxf(o1.z, 0.f); o1.w = fmaxf(o1.w, 0.f);
    }
    union { __half2 h2[4]; float4 f; } pk;
    pk.h2[0] = __floats2half2_rn(o0.x, o0.y);
    pk.h2[1] = __floats2half2_rn(o0.z, o0.w);
    pk.h2[2] = __floats2half2_rn(o1.x, o1.y);
    pk.h2[3] = __floats2half2_rn(o1.z, o1.w);
    xout16[(size_t)d * 16 + gl] = pk.f;
}

// ---------------- global mean pool over fp16 x (batch is sorted) ------------
__global__ __launch_bounds__(512) void k_pool(const __half* __restrict__ x,
                                              const int* __restrict__ batch,
                                              float* __restrict__ out) {
    __shared__ float red[512];
    __shared__ int sh[2];
    int g = blockIdx.x;
    int t = threadIdx.x;
    if (t == 0) {
        int lo = 0, hi = N_NODES;
        while (lo < hi) { int mid = (lo + hi) >> 1; if (batch[mid] < g) lo = mid + 1; else hi = mid; }
        sh[0] = lo;
        int lo2 = lo, hi2 = N_NODES;
        while (lo2 < hi2) { int mid = (lo2 + hi2) >> 1; if (batch[mid] < g + 1) lo2 = mid + 1; else hi2 = mid; }
        sh[1] = lo2;
    }
    __syncthreads();
    int lo = sh[0], hi = sh[1];
    int sub = t >> 7, dim = t & 127;
    float sum = 0.f;
    for (int i = lo + sub; i < hi; i += 4) sum += __half2float(x[(size_t)i * 128 + dim]);
    red[t] = sum;
    __syncthreads();
    if (t < 128) {
        float s = red[t] + red[t + 128] + red[t + 256] + red[t + 384];
        int cnt = hi - lo;
        out[g * 128 + t] = s * (cnt > 0 ? 1.f / (float)cnt : 1.f);
    }
}

extern "C" void kernel_launch(void* const* d_in, const int* in_sizes, int n_in,
                              void* d_out, int out_size, void* d_ws, size_t ws_size,
                              hipStream_t stream) {
    const int*   node_ids   = (const int*)d_in[0];
    const int*   edge_index = (const int*)d_in[1];   // [2][800000]
    const int*   batch      = (const int*)d_in[2];
    const float* emb        = (const float*)d_in[3];
    const float* W[3]  = {(const float*)d_in[4],  (const float*)d_in[8],  (const float*)d_in[12]};
    const float* As[3] = {(const float*)d_in[5],  (const float*)d_in[9],  (const float*)d_in[13]};
    const float* Ad[3] = {(const float*)d_in[6],  (const float*)d_in[10], (const float*)d_in[14]};
    const float* Bs[3] = {(const float*)d_in[7],  (const float*)d_in[11], (const float*)d_in[15]};

    char* ws = (char*)d_ws;
    size_t off = 0;
    auto alloc = [&](size_t bytes) {
        void* p = ws + off; off += (bytes + 255) & ~(size_t)255; return p;
    };
    _Float16* xH    = (_Float16*)alloc((size_t)N_NODES * 128 * 2);  // activations (fp16)
    _Float16* hH    = (_Float16*)alloc((size_t)N_NODES * 128 * 2);  // h gather table (fp16)
    float*  as_     = (float*)alloc((size_t)N_NODES * 4);
    float*  ad_     = (float*)alloc((size_t)N_NODES * 4);
    int*    gcur    = (int*)alloc((size_t)NBINS * 4);        // zeroed cursors
    int*    row_ptr = (int*)alloc((size_t)(N_NODES + 1) * 4);
    int*    recs    = (int*)alloc((size_t)NBINS * CAP * 4);  // 6.4 MB fixed regions
    int*    srcs    = (int*)alloc((size_t)N_EDGES * 4);
    (void)ws_size; (void)in_sizes; (void)n_in; (void)out_size;

    hipMemsetAsync(gcur, 0, (size_t)NBINS * 4, stream);

    // CSR build pass 1 (needs only edge_index)
    k_scat1<<<(N_EDGES + 4095) / 4096, 256, 0, stream>>>(edge_index, gcur, recs);

    // fused: gemm layer-0 (independent of CSR) || scat2 (needs scat1 output)
    k_gemm0_scat2<<<GEMM_BLOCKS + NB_COARSE, 256, 0, stream>>>(
            emb, node_ids, W[0], As[0], Ad[0], hH, as_, ad_,
            recs, gcur, row_ptr, srcs);

    for (int l = 0; l < 3; l++) {
        if (l > 0)
            k_gemm<<<GEMM_BLOCKS, 256, 0, stream>>>(
                     (const void*)xH, W[l], As[l], Ad[l], hH, as_, ad_);
        k_aggregate<<<(N_NODES * 16 + 255) / 256, 256, 0, stream>>>((const float4*)hH,
                 as_, ad_, row_ptr, srcs, (const float4*)Bs[l], (float4*)xH,
                 (l < 2) ? 1 : 0);
    }
    k_pool<<<N_GRAPHS, 512, 0, stream>>>((const __half*)xH, batch, (float*)d_out);
}